// Round 6
// baseline (554.220 us; speedup 1.0000x reference)
//
#include <hip/hip_runtime.h>
#include <hip/hip_bf16.h>

typedef __hip_bfloat16 bf16;

__device__ __forceinline__ float b2f(bf16 v) { return __bfloat162float(v); }
__device__ __forceinline__ bf16  f2b(float v) { return __float2bfloat16(v); }
__device__ __forceinline__ float blo(unsigned u) { return __uint_as_float(u << 16); }
__device__ __forceinline__ float bhi(unsigned u) { return __uint_as_float(u & 0xffff0000u); }

template<int F32>
__device__ __forceinline__ float ldin(const void* p, size_t i) {
  if (F32) return ((const float*)p)[i];
  return b2f(((const bf16*)p)[i]);
}
__device__ __forceinline__ float ldrt(const void* p, size_t i, int f) {
  return f ? ((const float*)p)[i] : b2f(((const bf16*)p)[i]);
}

// ---------------------------------------------------------------------------
// k_prep: detect dtype (per-block), convert conv+compress weights to fp32
// scratch layouts (wave-uniform s_load reads downstream), scatter fgc->maskf.
// segments: [0,49760) conv nets | cwf 32768 | cbf 64 | scatter 8192
//   => total 90784 items, 355 blocks.
// NOTE: nothing prepped here may be read by k_unzip (it overwrites scratch).
// ---------------------------------------------------------------------------
__global__ __launch_bounds__(256) void k_prep(
    const unsigned short* __restrict__ cFu,
    const void* __restrict__ s_w1, const void* __restrict__ s_b1,
    const void* __restrict__ s_w2, const void* __restrict__ s_b2,
    const void* __restrict__ s_w3, const void* __restrict__ s_b3,
    const void* __restrict__ c_w1, const void* __restrict__ c_b1,
    const void* __restrict__ c_w2, const void* __restrict__ c_b2,
    const void* __restrict__ c_w3, const void* __restrict__ c_b3,
    const void* __restrict__ cw,  const void* __restrict__ cb,
    const int* __restrict__ fgc,
    float* __restrict__ w1f, float* __restrict__ b1f,
    float* __restrict__ w2f, float* __restrict__ b2f,
    float* __restrict__ w3f, float* __restrict__ b3f,
    float* __restrict__ cwf, float* __restrict__ cbf,
    int* __restrict__ maskf, int* __restrict__ flag)
{
  __shared__ int sflag;
  const int tid = threadIdx.x;
  if (tid < 64) {
    int nb = 0;
    #pragma unroll
    for (int t = 0; t < 4; t++) {
      unsigned e = (cFu[tid * 4 + t] >> 7) & 0xFFu;
      nb += (e >= 0x90u) ? 1 : 0;
    }
    #pragma unroll
    for (int off = 32; off > 0; off >>= 1) nb += __shfl_down(nb, off);
    if (tid == 0) sflag = (nb > 8) ? 1 : 0;
  }
  __syncthreads();
  const int f = sflag;
  const int t = blockIdx.x * 256 + tid;
  if (blockIdx.x == 0 && tid == 0) flag[0] = f;
  if (t >= 90784) return;

  if (t < 49760) {                       // conv1/2/3 weights+biases, 2 nets
    const int net = (t >= 24880) ? 1 : 0;
    int r = t - net * 24880;
    const void* W1 = net ? c_w1 : s_w1;  const void* B1 = net ? c_b1 : s_b1;
    const void* W2 = net ? c_w2 : s_w2;  const void* B2 = net ? c_b2 : s_b2;
    const void* W3 = net ? c_w3 : s_w3;  const void* B3 = net ? c_b3 : s_b3;
    if (r < 1728) {                      // w1: [ch][27] -> [k][ch]
      int k = r >> 6, ch = r & 63;
      w1f[net * 1728 + r] = ldrt(W1, (size_t)ch * 27 + k, f);
      return;
    }
    r -= 1728;
    if (r < 64) { b1f[net * 64 + r] = ldrt(B1, r, f); return; }
    r -= 64;
    if (r < 18432) {                     // w2: [oc][576] -> [kk][oc]
      int oc = r & 31, kk = r >> 5;
      w2f[net * 18432 + r] = ldrt(W2, (size_t)oc * 576 + kk, f);
      return;
    }
    r -= 18432;
    if (r < 32) { b2f[net * 32 + r] = ldrt(B2, r, f); return; }
    r -= 32;
    if (r < 4608) {                      // w3: [oc][288] -> [kk][oc]
      int oc = r & 15, kk = r >> 4;
      w3f[net * 4608 + r] = ldrt(W3, (size_t)oc * 288 + kk, f);
      return;
    }
    r -= 4608;
    b3f[net * 16 + r] = ldrt(B3, r, f);
    return;
  }
  int r = t - 49760;
  if (r < 32768) {                       // cw: [oc][512] -> cwf [ch][64]
    int ch = r >> 6, oc = r & 63;
    cwf[r] = ldrt(cw, (size_t)oc * 512 + ch, f);
    return;
  }
  r -= 32768;
  if (r < 64) { cbf[r] = ldrt(cb, r, f); return; }
  r -= 64;
  maskf[fgc[r]] = 1;                     // scatter, r in [0,8192)
}

// ---------------------------------------------------------------------------
// FUSED conv1+conv2 (round-4 proven version, unchanged).
// ---------------------------------------------------------------------------
struct SmConv12 {
  bf16  ins[3][35][68];
  bf16  c1s[8][17][40];
  alignas(16) float w1a[27][64];
};

template<int F32>
__device__ __forceinline__ void conv12_body(
    const void* __restrict__ IN, const float* __restrict__ w1f_net,
    const float* __restrict__ b1f_net, const float* __restrict__ w2f_net,
    const float* __restrict__ b2f_net, bf16* __restrict__ OUT, SmConv12& sm)
{
  const int tid = threadIdx.x;
  const int R0 = blockIdx.y << 3;
  const int C0 = blockIdx.x << 4;

  const int ibr = 4 * R0 - 3, ibc = 4 * C0 - 3;
  for (int i = tid; i < 7140; i += 256) {
    int ch  = i / 2380;
    int rem = i - ch * 2380;
    int li = rem / 68, lc = rem - li * 68;
    int iy = ibr + li, ix = ibc + lc;
    float v = 0.f;
    if ((unsigned)iy < 1024u && (unsigned)ix < 1024u)
      v = ldin<F32>(IN, (size_t)ch * 1048576 + (size_t)iy * 1024 + ix);
    sm.ins[ch][li][lc] = f2b(v);
  }
  for (int i = tid; i < 1728; i += 256)
    (&sm.w1a[0][0])[i] = w1f_net[i];
  __syncthreads();

  const int og  = tid >> 7;
  const int ogu = __builtin_amdgcn_readfirstlane(og);
  const int p  = tid & 127;
  const int r  = p >> 4;
  const int c  = p & 15;

  float acc[16];
  #pragma unroll
  for (int j = 0; j < 16; j++) acc[j] = b2f_net[ogu * 16 + j];

  #pragma unroll 1
  for (int ss = 0; ss < 8; ss++) {
    if (ss) __syncthreads();
    const int ss8 = ss * 8;

    float bb[8];
    #pragma unroll
    for (int ch = 0; ch < 8; ch++) bb[ch] = b1f_net[ss8 + ch];

    for (int i = tid; i < 561; i += 256) {
      const int lr = i / 33, lc = i - lr * 33;
      const int g1r = 2 * R0 - 1 + lr, g1c = 2 * C0 - 1 + lc;
      if (((unsigned)g1r < 512u) && ((unsigned)g1c < 512u)) {
        float a1[8];
        #pragma unroll
        for (int ch = 0; ch < 8; ch++) a1[ch] = bb[ch];
        #pragma unroll
        for (int ic = 0; ic < 3; ic++) {
          #pragma unroll
          for (int ky = 0; ky < 3; ky++) {
            const int* rp = (const int*)&sm.ins[ic][2 * lr + ky][0];
            const unsigned u0 = (unsigned)rp[lc];
            const unsigned u1 = (unsigned)rp[lc + 1];
            const float v3[3] = { blo(u0), bhi(u0), blo(u1) };
            #pragma unroll
            for (int kx = 0; kx < 3; kx++) {
              const int k = ic * 9 + ky * 3 + kx;
              const float4 wA = *(const float4*)&sm.w1a[k][ss8];
              const float4 wB = *(const float4*)&sm.w1a[k][ss8 + 4];
              const float v = v3[kx];
              a1[0] += wA.x * v; a1[1] += wA.y * v;
              a1[2] += wA.z * v; a1[3] += wA.w * v;
              a1[4] += wB.x * v; a1[5] += wB.y * v;
              a1[6] += wB.z * v; a1[7] += wB.w * v;
            }
          }
        }
        #pragma unroll
        for (int ch = 0; ch < 8; ch++)
          sm.c1s[ch][lr][lc] = f2b(fmaxf(a1[ch], 0.f));
      } else {
        #pragma unroll
        for (int ch = 0; ch < 8; ch++) sm.c1s[ch][lr][lc] = f2b(0.f);
      }
    }
    __syncthreads();

    const float* __restrict__ W2F = w2f_net + (size_t)ss * 72 * 32 + ogu * 16;
    #pragma unroll
    for (int icl = 0; icl < 8; icl++) {
      float cv[3][3];
      #pragma unroll
      for (int ky = 0; ky < 3; ky++) {
        const int* cp = (const int*)&sm.c1s[icl][2 * r + ky][0];
        const unsigned u0 = (unsigned)cp[c];
        const unsigned u1 = (unsigned)cp[c + 1];
        cv[ky][0] = blo(u0); cv[ky][1] = bhi(u0); cv[ky][2] = blo(u1);
      }
      #pragma unroll
      for (int ky = 0; ky < 3; ky++) {
        #pragma unroll
        for (int kx = 0; kx < 3; kx++) {
          const int kk = icl * 9 + ky * 3 + kx;
          const float v = cv[ky][kx];
          const float* wr = W2F + kk * 32;
          #pragma unroll
          for (int j4 = 0; j4 < 4; j4++) {
            const float4 w4 = *(const float4*)&wr[j4 * 4];
            acc[j4 * 4 + 0] += w4.x * v; acc[j4 * 4 + 1] += w4.y * v;
            acc[j4 * 4 + 2] += w4.z * v; acc[j4 * 4 + 3] += w4.w * v;
          }
        }
      }
    }
  }

  const size_t sp = (size_t)(R0 + r) * 256 + (C0 + c);
  #pragma unroll
  for (int j = 0; j < 16; j++)
    OUT[(size_t)(og * 16 + j) * 65536 + sp] = f2b(fmaxf(acc[j], 0.f));
}

__global__ __launch_bounds__(256) void k_conv12(
    const void* __restrict__ in0, const void* __restrict__ in1,
    const float* __restrict__ w1f, const float* __restrict__ b1f,
    const float* __restrict__ w2f, const float* __restrict__ b2f,
    bf16* __restrict__ c2o, const int* __restrict__ flag)
{
  __shared__ SmConv12 sm;
  const int n = blockIdx.z;
  const void* IN = n ? in1 : in0;
  const float* W1 = w1f + n * 1728;
  const float* B1 = b1f + n * 64;
  const float* W2 = w2f + n * 18432;
  const float* B2 = b2f + n * 32;
  bf16* OUT = c2o + (size_t)n * 2097152;
  if (flag[0]) conv12_body<1>(IN, W1, B1, W2, B2, OUT, sm);
  else         conv12_body<0>(IN, W1, B1, W2, B2, OUT, sm);
}

// ---------------------------------------------------------------------------
// FUSED conv3 + compress (+mean partials via atomicAdd).
// ---------------------------------------------------------------------------
template<int F32>
__device__ __forceinline__ void compress_part(
    const void* __restrict__ cF, const float* __restrict__ cwf,
    const float* __restrict__ cbf, float* __restrict__ ccf,
    float* __restrict__ meanRaw, int b, int tid, float (*red)[17])
{
  const int og = __builtin_amdgcn_readfirstlane(b >> 7);   // 0..3
  const int sx = b & 127;
  const int sl = tid & 127, half = tid >> 7;
  const int halfu = __builtin_amdgcn_readfirstlane(half);
  const int s = sx * 128 + sl;
  float acc[16];
  #pragma unroll
  for (int j = 0; j < 16; j++) acc[j] = half ? 0.f : cbf[og * 16 + j];
  const float* __restrict__ WB = cwf + (size_t)halfu * 256 * 64 + og * 16;
  #pragma unroll 4
  for (int ci = 0; ci < 256; ci++) {
    const int ch = halfu * 256 + ci;
    const float v = ldin<F32>(cF, (size_t)ch * 16384 + s);
    const float* wr = WB + ci * 64;
    #pragma unroll
    for (int j4 = 0; j4 < 4; j4++) {
      const float4 w4 = *(const float4*)&wr[j4 * 4];
      acc[j4 * 4 + 0] += w4.x * v; acc[j4 * 4 + 1] += w4.y * v;
      acc[j4 * 4 + 2] += w4.z * v; acc[j4 * 4 + 3] += w4.w * v;
    }
  }
  if (half) {
    #pragma unroll
    for (int j = 0; j < 16; j++) red[sl][j] = acc[j];
  }
  __syncthreads();
  if (!half) {
    float fin[16];
    #pragma unroll
    for (int j = 0; j < 16; j++) fin[j] = acc[j] + red[sl][j];
    #pragma unroll
    for (int j = 0; j < 16; j++)
      ccf[(size_t)(og * 16 + j) * 16384 + s] = fin[j];
    const int lane = tid & 63;
    #pragma unroll
    for (int j = 0; j < 16; j++) {
      float rr = fin[j];
      #pragma unroll
      for (int off = 32; off > 0; off >>= 1) rr += __shfl_down(rr, off);
      if (lane == 0) atomicAdd(&meanRaw[og * 16 + j], rr);
    }
  }
}

__global__ __launch_bounds__(256) void k_c3cmp(
    const bf16* __restrict__ c2o,
    const float* __restrict__ w3f, const float* __restrict__ b3f,
    float* __restrict__ c3o,
    const void* __restrict__ cF, const float* __restrict__ cwf,
    const float* __restrict__ cbf, float* __restrict__ ccf,
    float* __restrict__ meanRaw, const int* __restrict__ flag)
{
  __shared__ float red[128][17];
  const int bx = blockIdx.x;
  const int tid = threadIdx.x;
  if (bx < 512) {
    const int n = bx >> 8;
    const int ocg = __builtin_amdgcn_readfirstlane((bx >> 6) & 3);
    const int sx = bx & 63;
    const bf16* __restrict__ IN = c2o + (size_t)n * 32 * 65536;
    const float* __restrict__ WF = w3f + (size_t)n * 4608 + ocg * 4;
    const int s = sx * 256 + tid;
    const int oy = s >> 7, ox = s & 127;
    float acc[4];
    #pragma unroll
    for (int j = 0; j < 4; j++) acc[j] = b3f[n * 16 + ocg * 4 + j];
    #pragma unroll 2
    for (int ic = 0; ic < 32; ic++) {
      const int* __restrict__ I32 = (const int*)(IN + (size_t)ic * 65536);
      #pragma unroll
      for (int ky = 0; ky < 3; ky++) {
        const int iy = 2 * oy + ky - 1;
        const bool oky = (unsigned)iy < 256u;
        const int rb = iy * 128;
        const unsigned um = (oky && ox > 0) ? (unsigned)I32[rb + ox - 1] : 0u;
        const unsigned u0 = oky ? (unsigned)I32[rb + ox] : 0u;
        const float v3[3] = { bhi(um), blo(u0), bhi(u0) };
        #pragma unroll
        for (int kx = 0; kx < 3; kx++) {
          const int kk = ic * 9 + ky * 3 + kx;
          const float4 w4 = *(const float4*)&WF[kk * 16];
          const float v = v3[kx];
          acc[0] += w4.x * v; acc[1] += w4.y * v;
          acc[2] += w4.z * v; acc[3] += w4.w * v;
        }
      }
    }
    float* O = c3o + (size_t)n * 16 * 16384;
    #pragma unroll
    for (int j = 0; j < 4; j++) O[(size_t)(ocg * 4 + j) * 16384 + s] = acc[j];
    return;
  }
  const int b = bx - 512;
  if (flag[0]) compress_part<1>(cF, cwf, cbf, ccf, meanRaw, b, tid, red);
  else         compress_part<0>(cF, cwf, cbf, ccf, meanRaw, b, tid, red);
}

// ---------------------------------------------------------------------------
// gather + maxpool
// ---------------------------------------------------------------------------
__global__ __launch_bounds__(256) void k_pool(
    const float* __restrict__ feat,
    const int* __restrict__ fgs, const int* __restrict__ fgc,
    float* __restrict__ pooled)
{
  int t = blockIdx.x * 256 + threadIdx.x;
  int n = t >> 12, rem = t & 4095;
  int c = rem >> 8, p = rem & 255;
  const int* __restrict__ m = n ? fgc : fgs;
  const float* __restrict__ F = feat + (size_t)n * 16 * 16384 + (size_t)c * 16384;
  float mx = -3.4e38f;
  #pragma unroll 4
  for (int j = 0; j < 32; j++) mx = fmaxf(mx, F[m[p * 32 + j]]);
  pooled[(size_t)n * 4096 + rem] = mx;
}

// ---------------------------------------------------------------------------
// FC (vectorized weights, shuffle reduce)
// ---------------------------------------------------------------------------
__global__ __launch_bounds__(256) void k_fc(
    const float* __restrict__ pooled,
    const void* __restrict__ w0, const void* __restrict__ bb0,
    const void* __restrict__ w1, const void* __restrict__ bb1,
    float* __restrict__ mats, const int* __restrict__ flag)
{
  __shared__ float red[4];
  const int n = blockIdx.z;
  const int i = blockIdx.x;
  const void* W = n ? w1  : w0;
  const void* B = n ? bb1 : bb0;
  const float* __restrict__ P = pooled + (size_t)n * 4096;
  const int tid = threadIdx.x;
  const int f = flag[0];

  const float4* P4 = (const float4*)(P + (size_t)tid * 16);
  const float4 p0 = P4[0], p1 = P4[1], p2 = P4[2], p3 = P4[3];
  float p;
  if (f) {
    const float4* W4 = (const float4*)((const float*)W + (size_t)i * 4096 + tid * 16);
    const float4 w0v = W4[0], w1v = W4[1], w2v = W4[2], w3v = W4[3];
    p = w0v.x*p0.x + w0v.y*p0.y + w0v.z*p0.z + w0v.w*p0.w
      + w1v.x*p1.x + w1v.y*p1.y + w1v.z*p1.z + w1v.w*p1.w
      + w2v.x*p2.x + w2v.y*p2.y + w2v.z*p2.z + w2v.w*p2.w
      + w3v.x*p3.x + w3v.y*p3.y + w3v.z*p3.z + w3v.w*p3.w;
  } else {
    const int4* Wb = (const int4*)((const bf16*)W + (size_t)i * 4096 + tid * 16);
    const int4 a = Wb[0], b = Wb[1];
    p = blo((unsigned)a.x)*p0.x + bhi((unsigned)a.x)*p0.y
      + blo((unsigned)a.y)*p0.z + bhi((unsigned)a.y)*p0.w
      + blo((unsigned)a.z)*p1.x + bhi((unsigned)a.z)*p1.y
      + blo((unsigned)a.w)*p1.z + bhi((unsigned)a.w)*p1.w
      + blo((unsigned)b.x)*p2.x + bhi((unsigned)b.x)*p2.y
      + blo((unsigned)b.y)*p2.z + bhi((unsigned)b.y)*p2.w
      + blo((unsigned)b.z)*p3.x + bhi((unsigned)b.z)*p3.y
      + blo((unsigned)b.w)*p3.z + bhi((unsigned)b.w)*p3.w;
  }
  #pragma unroll
  for (int off = 32; off > 0; off >>= 1) p += __shfl_down(p, off);
  if ((tid & 63) == 0) red[tid >> 6] = p;
  __syncthreads();
  if (tid == 0) {
    float b = f ? ((const float*)B)[i] : b2f(((const bf16*)B)[i]);
    mats[(size_t)n * 4096 + i] = red[0] + red[1] + red[2] + red[3] + b;
  }
}

// ---------------------------------------------------------------------------
// transform (+tmat folded)
// ---------------------------------------------------------------------------
__global__ __launch_bounds__(256) void k_transform(
    const float* __restrict__ ccf, const float* __restrict__ mats,
    const float* __restrict__ meanRaw, const int* __restrict__ maskf,
    bf16* __restrict__ tf)
{
  const int og = blockIdx.y;                // 0..7
  __shared__ __align__(16) float Tl[8][64];
  __shared__ float ml[64];
  const int tid = threadIdx.x;
  const float* __restrict__ S = mats;
  const float* __restrict__ C = mats + 4096;
  #pragma unroll
  for (int u = 0; u < 2; u++) {
    const int idx = tid + u * 256;          // 0..511
    const int row = idx >> 6, col = idx & 63;
    const float* Sr = S + (size_t)(og * 8 + row) * 64;
    float a = 0.f;
    #pragma unroll 8
    for (int k = 0; k < 64; k++) a += Sr[k] * C[k * 64 + col];
    Tl[row][col] = a;
  }
  if (tid < 64) ml[tid] = meanRaw[tid] * (1.f / 16384.f);
  __syncthreads();
  const int s = blockIdx.x * 256 + tid;
  const bool msk = maskf[s] != 0;
  float col[64];
  #pragma unroll
  for (int op = 0; op < 64; op++) col[op] = ccf[(size_t)op * 16384 + s] - ml[op];
  #pragma unroll
  for (int ol = 0; ol < 8; ol++) {
    float a = 0.f;
    #pragma unroll
    for (int op4 = 0; op4 < 16; op4++) {
      float4 t4 = *(const float4*)&Tl[ol][op4 * 4];
      a += t4.x * col[op4 * 4 + 0] + t4.y * col[op4 * 4 + 1]
         + t4.z * col[op4 * 4 + 2] + t4.w * col[op4 * 4 + 3];
    }
    const int row = og * 8 + ol;
    tf[(size_t)row * 16384 + s] = f2b(msk ? a : col[row]);
  }
}

// ---------------------------------------------------------------------------
// unzip: reads ONLY input buffers (uw/ub raw) + tf (d_ws) — it overwrites
// d_out scratch while running, so it must not read anything from there.
// dtype flag recomputed per-block from cF.
// ---------------------------------------------------------------------------
struct SmUnzip { alignas(16) float wl[64][32]; float bl[32]; int f; };

__global__ __launch_bounds__(256) void k_unzip(
    const bf16* __restrict__ tf, const void* __restrict__ uw,
    const void* __restrict__ ub, void* __restrict__ outp,
    const unsigned short* __restrict__ cFu)
{
  __shared__ SmUnzip sm;
  const int tid = threadIdx.x;
  if (tid < 64) {
    int nb = 0;
    #pragma unroll
    for (int t = 0; t < 4; t++) {
      unsigned e = (cFu[tid * 4 + t] >> 7) & 0xFFu;
      nb += (e >= 0x90u) ? 1 : 0;
    }
    #pragma unroll
    for (int off = 32; off > 0; off >>= 1) nb += __shfl_down(nb, off);
    if (tid == 0) sm.f = (nb > 8) ? 1 : 0;
  }
  __syncthreads();
  const int f = sm.f;
  const int ug = blockIdx.y;
  for (int i = tid; i < 2048; i += 256) {
    int ul = i & 31, o = i >> 5;
    sm.wl[o][ul] = ldrt(uw, (size_t)(ug * 32 + ul) * 64 + o, f);
  }
  if (tid < 32) sm.bl[tid] = ldrt(ub, ug * 32 + tid, f);
  __syncthreads();
  const int s = blockIdx.x * 256 + tid;
  float acc[32];
  #pragma unroll
  for (int j = 0; j < 32; j++) acc[j] = sm.bl[j];
  #pragma unroll 4
  for (int o = 0; o < 64; o++) {
    const float v = b2f(tf[(size_t)o * 16384 + s]);
    #pragma unroll
    for (int j4 = 0; j4 < 8; j4++) {
      const float4 w4 = *(const float4*)&sm.wl[o][j4 * 4];
      acc[j4 * 4 + 0] += w4.x * v; acc[j4 * 4 + 1] += w4.y * v;
      acc[j4 * 4 + 2] += w4.z * v; acc[j4 * 4 + 3] += w4.w * v;
    }
  }
  if (f) {
    float* O = (float*)outp;
    #pragma unroll
    for (int j = 0; j < 32; j++)
      O[(size_t)(ug * 32 + j) * 16384 + s] = acc[j];
  } else {
    bf16* O = (bf16*)outp;
    #pragma unroll
    for (int j = 0; j < 32; j++)
      O[(size_t)(ug * 32 + j) * 16384 + s] = f2b(acc[j]);
  }
}

// ---------------------------------------------------------------------------
extern "C" void kernel_launch(void* const* d_in, const int* in_sizes, int n_in,
                              void* d_out, int out_size, void* d_ws, size_t ws_size,
                              hipStream_t stream)
{
  const void* cF      = d_in[0];
  const void* content = d_in[2];
  const void* style   = d_in[3];
  const void* s_c1w = d_in[4];  const void* s_c1b = d_in[5];
  const void* s_c2w = d_in[6];  const void* s_c2b = d_in[7];
  const void* s_c3w = d_in[8];  const void* s_c3b = d_in[9];
  const void* s_fcw = d_in[10]; const void* s_fcb = d_in[11];
  const void* c_c1w = d_in[12]; const void* c_c1b = d_in[13];
  const void* c_c2w = d_in[14]; const void* c_c2b = d_in[15];
  const void* c_c3w = d_in[16]; const void* c_c3b = d_in[17];
  const void* c_fcw = d_in[18]; const void* c_fcb = d_in[19];
  const void* cw = d_in[20];    const void* cb = d_in[21];
  const void* uw = d_in[22];    const void* ub = d_in[23];
  const int* fgc = (const int*)d_in[24];
  const int* fgs = (const int*)d_in[25];
  (void)in_sizes; (void)n_in; (void)out_size; (void)ws_size;

  // ---- scratch inside d_out; final k_unzip reads NOTHING from d_out.
  char* ob = (char*)d_out;
  bf16*  c2o     = (bf16*)(ob + 0);          // [2][32][65536] bf16  8,388,608 B
  float* c3o     = (float*)(ob + 8388608);   // [2][16][16384] f32   2,097,152 B
  float* ccf     = (float*)(ob + 10485760);  // [64][16384]  f32     4,194,304 B
  float* pooled  = (float*)(ob + 14680064);  //                         32,768 B
  float* mats    = (float*)(ob + 14712832);  //                         32,768 B
  int*   maskf   = (int*)(ob + 14745600);    // [16384]                 65,536 B
  float* meanRaw = (float*)(ob + 14811136);  // [64]+pad                 1,024 B
  int*   flag    = (int*)(ob + 14812160);    //                            256 B
  float* w1f     = (float*)(ob + 14812416);  // [2][27][64]             13,824 B
  float* b1f     = (float*)(ob + 14826240);  //                            512 B
  float* w2f     = (float*)(ob + 14826752);  // [2][576][32]           147,456 B
  float* b2f     = (float*)(ob + 14974208);  //                            256 B
  float* w3f     = (float*)(ob + 14974464);  // [2][288][16]            36,864 B
  float* b3f     = (float*)(ob + 15011328);  //                            128 B
  float* cwf     = (float*)(ob + 15011456);  // [512][64]              131,072 B
  float* cbf     = (float*)(ob + 15142528);  //                            256 B

  bf16* tf = (bf16*)d_ws;

  // 1) zero maskf + meanRaw (contiguous)
  (void)hipMemsetAsync(maskf, 0, 65792, stream);
  // 2) prep: flag + weight conversions + scatter
  k_prep<<<355, 256, 0, stream>>>(
      (const unsigned short*)cF,
      s_c1w, s_c1b, s_c2w, s_c2b, s_c3w, s_c3b,
      c_c1w, c_c1b, c_c2w, c_c2b, c_c3w, c_c3b,
      cw, cb, fgc,
      w1f, b1f, w2f, b2f, w3f, b3f, cwf, cbf, maskf, flag);
  // 3) fused conv1+conv2
  k_conv12<<<dim3(16, 32, 2), 256, 0, stream>>>(
      style, content, w1f, b1f, w2f, b2f, c2o, flag);
  // 4) fused conv3 + compress(+mean partials)
  k_c3cmp<<<1024, 256, 0, stream>>>(c2o, w3f, b3f, c3o,
                                    cF, cwf, cbf, ccf, meanRaw, flag);
  // 5) pool
  k_pool<<<32, 256, 0, stream>>>(c3o, fgs, fgc, pooled);
  // 6) fc
  k_fc<<<dim3(4096, 1, 2), 256, 0, stream>>>(pooled, s_fcw, s_fcb, c_fcw, c_fcb, mats, flag);
  // 7) transform (+tmat folded)
  k_transform<<<dim3(64, 8), 256, 0, stream>>>(ccf, mats, meanRaw, maskf, tf);
  // 8) unzip (reads only inputs + d_ws)
  k_unzip<<<dim3(64, 16), 256, 0, stream>>>(tf, uw, ub, d_out, (const unsigned short*)cF);
}